// Round 2
// baseline (936.103 us; speedup 1.0000x reference)
//
#include <hip/hip_runtime.h>
#include <hip/hip_bf16.h>

#define NB 64
#define ND 1500
#define NT 1000
#define NA 512
#define DP 1504   // D padded to multiple of 32 (zero-filled) for w1^T staging

typedef __bf16 bf16x8 __attribute__((ext_vector_type(8)));
typedef float  f32x4  __attribute__((ext_vector_type(4)));

// ---------------- kernel 0: w1 fp32 [D,NA] -> bf16 w1t [NA, DP] (zero-padded) ----------------
__global__ void w1t_kernel(const float* __restrict__ w1, __bf16* __restrict__ w1t) {
    int idx = blockIdx.x * 256 + threadIdx.x;
    if (idx >= NA * DP) return;
    int a = idx / DP, d = idx - a * DP;
    w1t[idx] = (d < ND) ? (__bf16)w1[d * NA + a] : (__bf16)0.0f;
}

// ---------------- kernel 1: scores[b,t] = sum_a relu(sum_d w1[d,a] X[b,d,t] + b1[a]) * w2[a] ----
// MFMA 16x16x32 bf16: M=a (64/block), N=t (64/block), K=d. Partial over a-chunk -> atomicAdd.
// X is fp32; converted to bf16 in-register during LDS staging.
__global__ __launch_bounds__(256) void score_kernel(
    const float* __restrict__ X,         // [B, D, T] fp32
    const __bf16* __restrict__ w1t,      // [NA, DP] a-major, k contiguous, bf16
    const float* __restrict__ b1,
    const float* __restrict__ w2,
    float* __restrict__ scores)          // [B, T] fp32, pre-zeroed
{
    constexpr int KP = 40;               // padded LDS row stride (elems)
    __shared__ __bf16 As[64 * KP];       // [a][k]
    __shared__ __bf16 Bs[64 * KP];       // [t][k^swz]
    __shared__ float b1s[64];
    __shared__ float w2s[64];

    const int ac = blockIdx.x;           // a-chunk fastest -> adjacent blocks reuse X tile in L2
    const int tt = blockIdx.y;
    const int b  = blockIdx.z;
    const int a0 = ac * 64;
    const int t0 = tt * 64;
    const int tid = threadIdx.x;

    if (tid < 64) {
        b1s[tid] = b1[a0 + tid];
        w2s[tid] = w2[a0 + tid];
    }

    const int lane = tid & 63;
    const int wave = tid >> 6;
    const int wm = wave & 1;             // waves 2x2 over (M,N)
    const int wn = wave >> 1;
    const int col = lane & 15;
    const int quad = lane >> 4;

    // staging maps
    const int a_row = tid >> 2;          // 0..63  (a within chunk)
    const int a_dc  = (tid & 3) << 3;    // k offset 0/8/16/24
    const int x_dr  = tid >> 3;          // 0..31  (d within K-tile)
    const int x_tc8 = tid & 7;           // 8-wide t chunk
    const int x_t   = x_tc8 << 3;
    const int x_sw  = (x_tc8 & 3) << 3;  // XOR swizzle: breaks bank conflicts on transpose writes

    const __bf16* w1p = w1t + (size_t)(a0 + a_row) * DP + a_dc;
    const float* xp   = X + (size_t)b * (ND * NT) + t0 + x_t;
    const bool tvalid = (t0 + x_t) < NT;  // T=1000 is 8-aligned -> whole-vector guard

    f32x4 acc[2][2] = {};

    for (int k0 = 0; k0 < ND; k0 += 32) {
        bf16x8 av = *(const bf16x8*)(w1p + k0);            // padded: always in-bounds, pad = 0
        float xr[8];
        #pragma unroll
        for (int j = 0; j < 8; ++j) xr[j] = 0.0f;
        if (tvalid && (k0 + x_dr) < ND) {
            const float* src = xp + (size_t)(k0 + x_dr) * NT;
            float4 u0 = *(const float4*)src;
            float4 u1 = *(const float4*)(src + 4);
            xr[0] = u0.x; xr[1] = u0.y; xr[2] = u0.z; xr[3] = u0.w;
            xr[4] = u1.x; xr[5] = u1.y; xr[6] = u1.z; xr[7] = u1.w;
        }

        __syncthreads();                                   // previous iter's frag reads done
        *(bf16x8*)(As + a_row * KP + a_dc) = av;
        #pragma unroll
        for (int j = 0; j < 8; ++j)                        // transpose: t-run -> k-contiguous rows
            Bs[(x_t + j) * KP + (x_dr ^ x_sw)] = (__bf16)xr[j];
        __syncthreads();

        bf16x8 af[2], bq[2];
        #pragma unroll
        for (int i = 0; i < 2; ++i) {
            af[i] = *(const bf16x8*)(As + (wm * 32 + i * 16 + col) * KP + quad * 8);
            int tl = wn * 32 + i * 16 + col;
            bq[i] = *(const bf16x8*)(Bs + tl * KP + ((quad ^ ((tl >> 3) & 3)) << 3));
        }
        #pragma unroll
        for (int im = 0; im < 2; ++im)
            #pragma unroll
            for (int in = 0; in < 2; ++in)
                acc[im][in] = __builtin_amdgcn_mfma_f32_16x16x32_bf16(
                    af[im], bq[in], acc[im][in], 0, 0, 0);
    }

    // epilogue: relu(+b1)*w2, reduce over a (rows), atomicAdd per t
    #pragma unroll
    for (int in = 0; in < 2; ++in) {
        float part = 0.f;
        #pragma unroll
        for (int im = 0; im < 2; ++im) {
            #pragma unroll
            for (int r = 0; r < 4; ++r) {
                int al = wm * 32 + im * 16 + quad * 4 + r;   // C/D: row = quad*4+reg
                float h = acc[im][in][r] + b1s[al];
                part += fmaxf(h, 0.f) * w2s[al];
            }
        }
        part += __shfl_down(part, 32);                        // reduce across quads (same col)
        part += __shfl_down(part, 16);
        int t = t0 + wn * 32 + in * 16 + col;                 // C/D: col = lane&15
        if (quad == 0 && t < NT)
            atomicAdd(scores + b * NT + t, part);
    }
}

// ---------------- kernel 2: softmax over t, write A fp32 into d_out ----------------
__global__ __launch_bounds__(256) void softmax_kernel(
    const float* __restrict__ scores, float* __restrict__ A_out)
{
    __shared__ float red[256];
    const int b = blockIdx.x, tid = threadIdx.x;
    const float* s = scores + b * NT;
    float v[4], m = -1e30f;
    #pragma unroll
    for (int i = 0; i < 4; ++i) {
        int t = tid + i * 256;
        v[i] = (t < NT) ? s[t] : -1e30f;
        m = fmaxf(m, v[i]);
    }
    red[tid] = m; __syncthreads();
    for (int off = 128; off > 0; off >>= 1) {
        if (tid < off) red[tid] = fmaxf(red[tid], red[tid + off]);
        __syncthreads();
    }
    m = red[0]; __syncthreads();
    float sum = 0.f;
    #pragma unroll
    for (int i = 0; i < 4; ++i) {
        v[i] = __expf(v[i] - m);
        if (tid + i * 256 < NT) sum += v[i]; else v[i] = 0.f;
    }
    red[tid] = sum; __syncthreads();
    for (int off = 128; off > 0; off >>= 1) {
        if (tid < off) red[tid] += red[tid + off];
        __syncthreads();
    }
    float inv = 1.f / red[0];
    #pragma unroll
    for (int i = 0; i < 4; ++i) {
        int t = tid + i * 256;
        if (t < NT) A_out[b * NT + t] = v[i] * inv;
    }
}

// ---------------- kernel 3: E, std pooling. wave per d-row, coalesced over t ----------------
__global__ __launch_bounds__(256) void pool_kernel(
    const float* __restrict__ X, const float* __restrict__ A,   // A = d_out[0:NB*NT]
    float* __restrict__ outE)                                   // d_out + NB*NT
{
    __shared__ float As[NT];
    const int b = blockIdx.x;
    const int d0 = blockIdx.y << 2;
    const int tid = threadIdx.x;
    for (int t = tid; t < NT; t += 256) As[t] = A[b * NT + t];
    __syncthreads();
    const int wave = tid >> 6, lane = tid & 63;
    const int d = d0 + wave;
    const float* x = X + (size_t)b * (ND * NT) + (size_t)d * NT;
    float e = 0.f, q = 0.f;
    #pragma unroll
    for (int it = 0; it < 4; ++it) {
        int t = it * 256 + (lane << 2);
        if (t < NT) {                                  // 1000 % 4 == 0 -> whole-vector guard
            float4 xv = *(const float4*)(x + t);
            float4 a4 = *(const float4*)(As + t);
            e += xv.x * a4.x + xv.y * a4.y + xv.z * a4.z + xv.w * a4.w;
            q += xv.x * xv.x * a4.x + xv.y * xv.y * a4.y + xv.z * xv.z * a4.z + xv.w * xv.w * a4.w;
        }
    }
    #pragma unroll
    for (int off = 32; off > 0; off >>= 1) {
        e += __shfl_down(e, off);
        q += __shfl_down(q, off);
    }
    if (lane == 0) {
        outE[b * 3000 + d] = e;
        outE[b * 3000 + 1500 + d] = sqrtf(fmaxf(q - e * e, 0.f) + 1e-5f);
    }
}

extern "C" void kernel_launch(void* const* d_in, const int* in_sizes, int n_in,
                              void* d_out, int out_size, void* d_ws, size_t ws_size,
                              hipStream_t stream) {
    const float* X  = (const float*)d_in[0];
    const float* w1 = (const float*)d_in[1];
    const float* b1 = (const float*)d_in[2];
    const float* w2 = (const float*)d_in[3];
    // d_in[4] = bias_2: scalar added to every t -> cancels in softmax over t; outputs unaffected.

    char* ws = (char*)d_ws;
    __bf16* w1t   = (__bf16*)ws;                         // NA*DP*2 = 1,540,096 B
    float*  scores = (float*)(ws + (size_t)NA * DP * 2); // NB*NT*4 =   256,000 B

    float* out = (float*)d_out;                          // [A : NB*NT][layer_out : NB*3000]

    hipMemsetAsync(scores, 0, (size_t)NB * NT * sizeof(float), stream);
    w1t_kernel<<<(NA * DP + 255) / 256, 256, 0, stream>>>(w1, w1t);
    score_kernel<<<dim3(NA / 64, 16, NB), 256, 0, stream>>>(X, w1t, b1, w2, scores);
    softmax_kernel<<<NB, 256, 0, stream>>>(scores, out);
    pool_kernel<<<dim3(NB, ND / 4), 256, 0, stream>>>(X, out, out + NB * NT);
}

// Round 3
// 831.670 us; speedup vs baseline: 1.1256x; 1.1256x over previous
//
#include <hip/hip_runtime.h>
#include <hip/hip_bf16.h>

#define NB 64
#define ND 1500
#define NT 1000
#define NA 512
#define DP 1504     // D padded to multiple of 32 (zero-filled) for w1^T
#define KSTEPS 47   // ceil(1500/32)
#define STR 17      // Bs t-stride in dwords (16 k-pair dwords + 1 pad)

typedef __bf16 bf16x8 __attribute__((ext_vector_type(8)));
typedef float  f32x4  __attribute__((ext_vector_type(4)));

union BQ { unsigned u[4]; bf16x8 v; };

static __device__ __forceinline__ unsigned pack2(float lo, float hi) {
    __bf16 l = (__bf16)lo, h = (__bf16)hi;
    unsigned short lu = __builtin_bit_cast(unsigned short, l);
    unsigned short hu = __builtin_bit_cast(unsigned short, h);
    return ((unsigned)hu << 16) | (unsigned)lu;
}

// ---------------- kernel 0: w1 fp32 [D,NA] -> bf16 w1t [NA, DP] (zero-padded) ----------------
__global__ void w1t_kernel(const float* __restrict__ w1, __bf16* __restrict__ w1t) {
    int idx = blockIdx.x * 256 + threadIdx.x;
    if (idx >= NA * DP) return;
    int a = idx / DP, d = idx - a * DP;
    w1t[idx] = (d < ND) ? (__bf16)w1[d * NA + a] : (__bf16)0.0f;
}

// ---------------- kernel 1: scores[b,t] = sum_a relu(sum_d w1[d,a] X[b,d,t] + b1[a]) * w2[a] ----
// One block per (t-tile, b). All 8 a-chunks in-block (acc[8][2][2]) -> X fetched from HBM once.
// A-frags loaded directly from w1t (L2-resident, k-contiguous). Bs: pair-packed dwords, stride 17.
__global__ __launch_bounds__(256, 2) void score_kernel(
    const float* __restrict__ X,         // [B, D, T] fp32
    const __bf16* __restrict__ w1t,      // [NA, DP]
    const float* __restrict__ b1,
    const float* __restrict__ w2,
    float* __restrict__ scores)          // [B, T] fp32
{
    __shared__ unsigned Bs[2][64 * STR];  // [t][k/2] pair-packed bf16, double-buffered
    __shared__ float b1s[NA], w2s[NA];
    __shared__ float ssc[64];

    const int tt = blockIdx.x;
    const int b  = blockIdx.y;
    const int t0 = tt * 64;
    const int tid = threadIdx.x;

    for (int i = tid; i < NA; i += 256) { b1s[i] = b1[i]; w2s[i] = w2[i]; }

    const int lane = tid & 63;
    const int wave = tid >> 6;
    const int wm = wave & 1;              // waves 2x2 over (a32, t32)
    const int wn = wave >> 1;
    const int col = lane & 15;
    const int quad = lane >> 4;

    // X staging map: thread handles d-pair (2*dr2, 2*dr2+1), 4 consecutive t
    const int dr2  = tid >> 4;            // 0..15
    const int toff = (tid & 15) << 2;     // 0..60
    const float* xbase = X + (size_t)b * (ND * NT) + (t0 + toff);
    const bool tval = (t0 + toff) < NT;   // T=1000, toff%4==0 -> whole-float4 guard

    // A-frag base: row (a) = ac*64 + wm*32 + im*16 + col, k offset quad*8
    const __bf16* w1a = w1t + (size_t)(wm * 32 + col) * DP + quad * 8;

    f32x4 acc[8][2][2];
    #pragma unroll
    for (int ac = 0; ac < 8; ++ac)
        #pragma unroll
        for (int im = 0; im < 2; ++im)
            #pragma unroll
            for (int in = 0; in < 2; ++in)
                acc[ac][im][in] = (f32x4){0.f, 0.f, 0.f, 0.f};

    // preload k=0 X tile and stage into Bs[0]
    float4 g0 = {0,0,0,0}, g1 = {0,0,0,0};
    {
        int d0 = 2 * dr2, d1 = d0 + 1;
        if (tval && d0 < ND) g0 = *(const float4*)(xbase + (size_t)d0 * NT);
        if (tval && d1 < ND) g1 = *(const float4*)(xbase + (size_t)d1 * NT);
        Bs[0][(toff + 0) * STR + dr2] = pack2(g0.x, g1.x);
        Bs[0][(toff + 1) * STR + dr2] = pack2(g0.y, g1.y);
        Bs[0][(toff + 2) * STR + dr2] = pack2(g0.z, g1.z);
        Bs[0][(toff + 3) * STR + dr2] = pack2(g0.w, g1.w);
    }

    for (int ks = 0; ks < KSTEPS; ++ks) {
        const int k0 = ks * 32;
        const int cur = ks & 1, nxt = cur ^ 1;

        // issue next k-tile's global loads first (deepest latency)
        float4 n0 = {0,0,0,0}, n1 = {0,0,0,0};
        {
            int d0 = k0 + 32 + 2 * dr2, d1 = d0 + 1;
            if (tval && d0 < ND) n0 = *(const float4*)(xbase + (size_t)d0 * NT);
            if (tval && d1 < ND) n1 = *(const float4*)(xbase + (size_t)d1 * NT);
        }

        __syncthreads();   // Bs[cur] writes from previous step visible

        // B-frags for this k-step (reused by all 8 a-chunks)
        bf16x8 bq[2];
        #pragma unroll
        for (int i = 0; i < 2; ++i) {
            int tl = wn * 32 + i * 16 + col;
            BQ q;
            #pragma unroll
            for (int jp = 0; jp < 4; ++jp)
                q.u[jp] = Bs[cur][tl * STR + quad * 4 + jp];
            bq[i] = q.v;
        }

        // A-frags for all 8 a-chunks: direct global (L2) loads, issued up-front
        const __bf16* wp = w1a + k0;
        bf16x8 af[8][2];
        #pragma unroll
        for (int ac = 0; ac < 8; ++ac) {
            af[ac][0] = *(const bf16x8*)(wp + (size_t)(ac * 64) * DP);
            af[ac][1] = *(const bf16x8*)(wp + (size_t)(ac * 64 + 16) * DP);
        }

        #pragma unroll
        for (int ac = 0; ac < 8; ++ac) {
            acc[ac][0][0] = __builtin_amdgcn_mfma_f32_16x16x32_bf16(af[ac][0], bq[0], acc[ac][0][0], 0, 0, 0);
            acc[ac][0][1] = __builtin_amdgcn_mfma_f32_16x16x32_bf16(af[ac][0], bq[1], acc[ac][0][1], 0, 0, 0);
            acc[ac][1][0] = __builtin_amdgcn_mfma_f32_16x16x32_bf16(af[ac][1], bq[0], acc[ac][1][0], 0, 0, 0);
            acc[ac][1][1] = __builtin_amdgcn_mfma_f32_16x16x32_bf16(af[ac][1], bq[1], acc[ac][1][1], 0, 0, 0);
        }

        // stage next k-tile (written before next barrier; other buffer, no race)
        Bs[nxt][(toff + 0) * STR + dr2] = pack2(n0.x, n1.x);
        Bs[nxt][(toff + 1) * STR + dr2] = pack2(n0.y, n1.y);
        Bs[nxt][(toff + 2) * STR + dr2] = pack2(n0.z, n1.z);
        Bs[nxt][(toff + 3) * STR + dr2] = pack2(n0.w, n1.w);
    }

    // ---------------- epilogue: full a-sum of relu(h+b1)*w2 per t ----------------
    float part[2] = {0.f, 0.f};
    #pragma unroll
    for (int ac = 0; ac < 8; ++ac)
        #pragma unroll
        for (int im = 0; im < 2; ++im)
            #pragma unroll
            for (int r = 0; r < 4; ++r) {
                int a = ac * 64 + wm * 32 + im * 16 + quad * 4 + r;
                float bb = b1s[a], ww = w2s[a];
                #pragma unroll
                for (int in = 0; in < 2; ++in) {
                    float h = acc[ac][im][in][r] + bb;
                    part[in] += fmaxf(h, 0.f) * ww;
                }
            }

    __syncthreads();
    if (tid < 64) ssc[tid] = 0.f;
    __syncthreads();
    #pragma unroll
    for (int in = 0; in < 2; ++in) {
        float p = part[in];
        p += __shfl_down(p, 32);   // quad 2,3 -> 0,1
        p += __shfl_down(p, 16);   // quad 1 -> 0
        if (quad == 0) atomicAdd(&ssc[wn * 32 + in * 16 + col], p);
    }
    __syncthreads();
    if (tid < 64) {
        int t = t0 + tid;
        if (t < NT) scores[b * NT + t] = ssc[tid];
    }
}

// ---------------- kernel 2: softmax over t, write A fp32 into d_out ----------------
__global__ __launch_bounds__(256) void softmax_kernel(
    const float* __restrict__ scores, float* __restrict__ A_out)
{
    __shared__ float red[256];
    const int b = blockIdx.x, tid = threadIdx.x;
    const float* s = scores + b * NT;
    float v[4], m = -1e30f;
    #pragma unroll
    for (int i = 0; i < 4; ++i) {
        int t = tid + i * 256;
        v[i] = (t < NT) ? s[t] : -1e30f;
        m = fmaxf(m, v[i]);
    }
    red[tid] = m; __syncthreads();
    for (int off = 128; off > 0; off >>= 1) {
        if (tid < off) red[tid] = fmaxf(red[tid], red[tid + off]);
        __syncthreads();
    }
    m = red[0]; __syncthreads();
    float sum = 0.f;
    #pragma unroll
    for (int i = 0; i < 4; ++i) {
        v[i] = __expf(v[i] - m);
        if (tid + i * 256 < NT) sum += v[i]; else v[i] = 0.f;
    }
    red[tid] = sum; __syncthreads();
    for (int off = 128; off > 0; off >>= 1) {
        if (tid < off) red[tid] += red[tid + off];
        __syncthreads();
    }
    float inv = 1.f / red[0];
    #pragma unroll
    for (int i = 0; i < 4; ++i) {
        int t = tid + i * 256;
        if (t < NT) A_out[b * NT + t] = v[i] * inv;
    }
}

// ---------------- kernel 3: E, std pooling. wave per d-row, coalesced over t ----------------
__global__ __launch_bounds__(256) void pool_kernel(
    const float* __restrict__ X, const float* __restrict__ A,   // A = d_out[0:NB*NT]
    float* __restrict__ outE)                                   // d_out + NB*NT
{
    __shared__ float As[NT];
    const int b = blockIdx.x;
    const int d0 = blockIdx.y << 2;
    const int tid = threadIdx.x;
    for (int t = tid; t < NT; t += 256) As[t] = A[b * NT + t];
    __syncthreads();
    const int wave = tid >> 6, lane = tid & 63;
    const int d = d0 + wave;
    const float* x = X + (size_t)b * (ND * NT) + (size_t)d * NT;
    float e = 0.f, q = 0.f;
    #pragma unroll
    for (int it = 0; it < 4; ++it) {
        int t = it * 256 + (lane << 2);
        if (t < NT) {                                  // 1000 % 4 == 0 -> whole-vector guard
            float4 xv = *(const float4*)(x + t);
            float4 a4 = *(const float4*)(As + t);
            e += xv.x * a4.x + xv.y * a4.y + xv.z * a4.z + xv.w * a4.w;
            q += xv.x * xv.x * a4.x + xv.y * xv.y * a4.y + xv.z * xv.z * a4.z + xv.w * xv.w * a4.w;
        }
    }
    #pragma unroll
    for (int off = 32; off > 0; off >>= 1) {
        e += __shfl_down(e, off);
        q += __shfl_down(q, off);
    }
    if (lane == 0) {
        outE[b * 3000 + d] = e;
        outE[b * 3000 + 1500 + d] = sqrtf(fmaxf(q - e * e, 0.f) + 1e-5f);
    }
}

extern "C" void kernel_launch(void* const* d_in, const int* in_sizes, int n_in,
                              void* d_out, int out_size, void* d_ws, size_t ws_size,
                              hipStream_t stream) {
    const float* X  = (const float*)d_in[0];
    const float* w1 = (const float*)d_in[1];
    const float* b1 = (const float*)d_in[2];
    const float* w2 = (const float*)d_in[3];
    // d_in[4] = bias_2: scalar added to every t -> cancels in softmax over t; outputs unaffected.

    char* ws = (char*)d_ws;
    __bf16* w1t    = (__bf16*)ws;                        // NA*DP*2 = 1,540,096 B
    float*  scores = (float*)(ws + (size_t)NA * DP * 2); // NB*NT*4 =   256,000 B

    float* out = (float*)d_out;                          // [A : NB*NT][layer_out : NB*3000]

    w1t_kernel<<<(NA * DP + 255) / 256, 256, 0, stream>>>(w1, w1t);
    score_kernel<<<dim3(16, NB), 256, 0, stream>>>(X, w1t, b1, w2, scores);
    softmax_kernel<<<NB, 256, 0, stream>>>(scores, out);
    pool_kernel<<<dim3(NB, ND / 4), 256, 0, stream>>>(X, out, out + NB * NT);
}